// Round 5
// baseline (13213.698 us; speedup 1.0000x reference)
//
#include <hip/hip_runtime.h>
#include <math.h>

// S2TLA block, fp32. B=4, L=65536 (256x256), C=96, HEADS=6, WS=8, HID=192.
// Workspace ~150 MiB; d_out doubles as scratch (x_msa, then h2).

#define LTOK   65536
#define NTOK   (4 * LTOK)        // 262144
#define NCHUNKQ 8
#define RPC (NTOK / NCHUNKQ)     // 32768 rows = 512 windows
#define PADK 102                 // LDS row pad: 2-way conflicts max

enum { EPI_PLAIN = 0, EPI_PROJ = 1, EPI_RSOUT = 2, EPI_FC1 = 3, EPI_FC2 = 4 };

// ---------------------------------------------------------------------------
// mod = silu(c) @ ada_w.T + ada_b   -> (4, 576)
// ---------------------------------------------------------------------------
__global__ __launch_bounds__(256)
void mod_kernel(const float* __restrict__ cvec, const float* __restrict__ ada_w,
                const float* __restrict__ ada_b, float* __restrict__ mod) {
  int idx = blockIdx.x * 256 + threadIdx.x;
  if (idx >= 4 * 576) return;
  int b = idx / 576, j = idx % 576;
  const float* cr = cvec + b * 96;
  float acc = ada_b[j];
  for (int c = 0; c < 96; ++c) {
    float cv = cr[c];
    acc += (cv / (1.f + expf(-cv))) * ada_w[j * 96 + c];
  }
  mod[idx] = acc;
}

// ---------------------------------------------------------------------------
// y = LN(x)*(1+sc)+sh per token. window_order=1 writes window-partitioned rows.
// ---------------------------------------------------------------------------
__global__ __launch_bounds__(256)
void ln_mod(const float* __restrict__ X, const float* __restrict__ lnw,
            const float* __restrict__ lnb, const float* __restrict__ mod,
            int sh_off, int sc_off, float* __restrict__ Y, int window_order) {
  int g = blockIdx.x * 4 + (threadIdx.x >> 6);
  int lane = threadIdx.x & 63;
  const float* xr = X + (size_t)g * 96;
  float2 v = make_float2(0.f, 0.f);
  if (lane < 48) v = *(const float2*)(xr + lane * 2);
  float s = v.x + v.y, sq = v.x * v.x + v.y * v.y;
#pragma unroll
  for (int m = 1; m < 64; m <<= 1) {
    s += __shfl_xor(s, m);
    sq += __shfl_xor(sq, m);
  }
  float mu = s * (1.f / 96.f);
  float rs = rsqrtf(sq * (1.f / 96.f) - mu * mu + 1e-5f);
  int b = g >> 16;
  size_t orow;
  if (window_order) {
    int l = g & 65535;
    int y = l >> 8, x = l & 255;
    orow = ((size_t)((b << 10) + ((y >> 3) << 5) + (x >> 3)) << 6) +
           ((y & 7) << 3) + (x & 7);
  } else {
    orow = g;
  }
  if (lane < 48) {
    int c = lane * 2;
    const float* mb = mod + b * 576;
    float2 o;
    o.x = ((v.x - mu) * rs * lnw[c] + lnb[c]) * (1.f + mb[sc_off + c]) + mb[sh_off + c];
    o.y = ((v.y - mu) * rs * lnw[c + 1] + lnb[c + 1]) * (1.f + mb[sc_off + c + 1]) + mb[sh_off + c + 1];
    *(float2*)(Y + orow * 96 + c) = o;
  }
}

// ---------------------------------------------------------------------------
// gemmB: Y[m,n] = sum_k X[m,k]*W[n,k] (+bias), fused epilogues.
// Block tile 128x96, thread tile 8x6 (14 ds_read_b128 per 192 FMA).
// KCH = K/96 (1 or 2). KCH==1: persistent mpb m-tiles, dbuf Xs + reg prefetch.
// ---------------------------------------------------------------------------
template <int EPI, int KCH>
__global__ __launch_bounds__(256)
void gemmB(const float* __restrict__ X, int ldx, const float* __restrict__ W,
           int N, const float* __restrict__ bias, float* __restrict__ Y,
           const float* __restrict__ aux, const float* __restrict__ mod,
           int mpb, int row0) {
  __shared__ float Xs[(KCH == 1 ? 2 : 1) * 128 * PADK];
  __shared__ float Ws[KCH * 96 * PADK];
  const int t = threadIdx.x;
  const int bn = blockIdx.y;
  const int tm = t >> 4, tn = t & 15;
  constexpr int K = KCH * 96;

  const float* Wb = W;
  if constexpr (EPI == EPI_RSOUT)
    Wb = W + (size_t)((blockIdx.x * mpb * 128) >> 16) * 9216;

  // stage W (bn-slice, all K chunks): 9*KCH float4 per thread, exact
#pragma unroll
  for (int i = 0; i < 9 * KCH; ++i) {
    int f = t + i * 256;
    int n = f / (24 * KCH);
    int k = (f % (24 * KCH)) * 4;
    int c = (KCH == 2 && k >= 96) ? 1 : 0;
    *(float4*)(&Ws[(c * 96 + n) * PADK + (k - c * 96)]) =
        *(const float4*)(Wb + (size_t)(bn * 96 + n) * K + k);
  }

  float acc[8][6];

  auto stageX = [&](int buf, int trow, int kc) {
#pragma unroll
    for (int i = 0; i < 12; ++i) {
      int f = t + i * 256;
      int m = f / 24, q = f % 24;
      *(float4*)(&Xs[buf * 128 * PADK + m * PADK + q * 4]) =
          *(const float4*)(X + (size_t)(trow + m) * ldx + kc * 96 + q * 4);
    }
  };

  auto compute = [&](int buf, int wc) {
#pragma unroll
    for (int kk = 0; kk < 96; kk += 4) {
      float4 xa[8], wv[6];
#pragma unroll
      for (int i = 0; i < 8; ++i)
        xa[i] = *(const float4*)(&Xs[buf * 128 * PADK + (tm * 8 + i) * PADK + kk]);
#pragma unroll
      for (int j = 0; j < 6; ++j)
        wv[j] = *(const float4*)(&Ws[(wc * 96 + tn * 6 + j) * PADK + kk]);
#pragma unroll
      for (int i = 0; i < 8; ++i)
#pragma unroll
        for (int j = 0; j < 6; ++j)
          acc[i][j] += xa[i].x * wv[j].x + xa[i].y * wv[j].y +
                       xa[i].z * wv[j].z + xa[i].w * wv[j].w;
    }
  };

  auto epilogue = [&](int trow) {
#pragma unroll
    for (int i = 0; i < 8; ++i) {
      const int row = trow + tm * 8 + i;
#pragma unroll
      for (int j = 0; j < 6; ++j) {
        const int col = bn * 96 + tn * 6 + j;
        float v = acc[i][j];
        if constexpr (EPI != EPI_RSOUT) v += bias[col];
        if constexpr (EPI == EPI_PLAIN) {
          Y[(size_t)row * N + col] = v;
        } else if constexpr (EPI == EPI_PROJ) {
          int win = row >> 6, n = row & 63;
          int b = win >> 10, wy = (win >> 5) & 31, wx = win & 31;
          int iy = n >> 3, ix = n & 7;
          int l = ((wy << 3) + iy) * 256 + (wx << 3) + ix;
          size_t oi = ((size_t)b * LTOK + l) * 96 + col;
          Y[oi] = aux[oi] + mod[b * 576 + 192 + col] * v;
        } else if constexpr (EPI == EPI_RSOUT) {
          size_t oi = (size_t)row * 96 + col;
          Y[oi] = aux[oi] + v;
        } else if constexpr (EPI == EPI_FC1) {
          Y[(size_t)row * N + col] =
              0.5f * v * (1.f + erff(v * 0.70710678118654752440f));
        } else {  // EPI_FC2
          int grow = row0 + row;
          int b = grow >> 16;
          size_t oi = (size_t)grow * 96 + col;
          Y[oi] = aux[oi] + mod[b * 576 + 480 + col] * v;
        }
      }
    }
  };

  if constexpr (KCH == 1) {
    const int bm0 = blockIdx.x * mpb;
    stageX(0, bm0 * 128, 0);
    __syncthreads();
    int cur = 0;
    for (int mt = 0; mt < mpb; ++mt) {
      const int trow = (bm0 + mt) * 128;
      const bool hasnext = (mt + 1 < mpb);
      float4 pf[12];
      if (hasnext) {
        const int ntrow = trow + 128;
#pragma unroll
        for (int i = 0; i < 12; ++i) {
          int f = t + i * 256;
          int m = f / 24, q = f % 24;
          pf[i] = *(const float4*)(X + (size_t)(ntrow + m) * ldx + q * 4);
        }
      }
#pragma unroll
      for (int i = 0; i < 8; ++i)
#pragma unroll
        for (int j = 0; j < 6; ++j) acc[i][j] = 0.f;
      compute(cur, 0);
      if (hasnext) {
#pragma unroll
        for (int i = 0; i < 12; ++i) {
          int f = t + i * 256;
          int m = f / 24, q = f % 24;
          *(float4*)(&Xs[(cur ^ 1) * 128 * PADK + m * PADK + q * 4]) = pf[i];
        }
      }
      epilogue(trow);
      __syncthreads();
      cur ^= 1;
    }
  } else {
    // KCH == 2 (fc2): two K chunks, single Xs buffer, mpb==1
    const int trow = blockIdx.x * 128;
#pragma unroll
    for (int i = 0; i < 8; ++i)
#pragma unroll
      for (int j = 0; j < 6; ++j) acc[i][j] = 0.f;
    stageX(0, trow, 0);
    __syncthreads();
    compute(0, 0);
    __syncthreads();
    stageX(0, trow, 1);
    __syncthreads();
    compute(0, 1);
    epilogue(trow);
  }
}

// ---------------------------------------------------------------------------
// Windowed strip attention (both halves) + LePE + channel shuffle.
// One block per 8x8 window; writes apre IN PLACE over its own H rows.
// ---------------------------------------------------------------------------
__global__ __launch_bounds__(256)
void win_attn(const float* __restrict__ qkv, const float* __restrict__ w0,
              const float* __restrict__ b0, const float* __restrict__ w1,
              const float* __restrict__ b1, float* __restrict__ apre) {
  __shared__ float skv[64 * 192];  // [n][0..95]=k, [n][96..191]=v
  const int t = threadIdx.x;
  const int win = blockIdx.x;
  const float* gb = qkv + (size_t)win * (64 * 288);
#pragma unroll
  for (int i = 0; i < 12; ++i) {
    int f = t + i * 256;
    int n = f / 48, q = f % 48;
    *(float4*)(&skv[n * 192 + q * 4]) = *(const float4*)(gb + n * 288 + 96 + q * 4);
  }
  __syncthreads();

  float P[2][8];
  int task[2];
#pragma unroll
  for (int it = 0; it < 2; ++it) {
    int tt = t + it * 256;
    task[it] = (tt < 384) ? tt : -1;
    if (task[it] < 0) continue;
    int br = tt / 192;
    int r = tt % 192;
    int stp = r / 24;
    int h = (r / 8) % 3;
    int e = r % 8;
    int cb = br ? 48 + h * 16 : h * 16;
    int ni = br ? stp * 8 + e : e * 8 + stp;
    float qreg[16];
#pragma unroll
    for (int d = 0; d < 16; ++d) qreg[d] = gb[ni * 288 + cb + d];
    float s[8];
#pragma unroll
    for (int j = 0; j < 8; ++j) {
      int nj = br ? stp * 8 + j : j * 8 + stp;
      float a = 0.f;
#pragma unroll
      for (int d = 0; d < 16; ++d) a += qreg[d] * skv[nj * 192 + cb + d];
      s[j] = a * 0.25f;
    }
    float mx = s[0];
#pragma unroll
    for (int j = 1; j < 8; ++j) mx = fmaxf(mx, s[j]);
    float sum = 0.f;
#pragma unroll
    for (int j = 0; j < 8; ++j) { s[j] = expf(s[j] - mx); sum += s[j]; }
    float inv = 1.f / sum;
#pragma unroll
    for (int j = 0; j < 8; ++j) P[it][j] = s[j] * inv;
  }
  __syncthreads();

#pragma unroll
  for (int it = 0; it < 2; ++it) {
    int tt = task[it];
    if (tt < 0) continue;
    int br = tt / 192;
    int r = tt % 192;
    int stp = r / 24;
    int h = (r / 8) % 3;
    int e = r % 8;
    int cb = br ? 48 + h * 16 : h * 16;
    int ni = br ? stp * 8 + e : e * 8 + stp;
    float outv[16];
#pragma unroll
    for (int d = 0; d < 16; ++d) {
      int c = cb + d;
      float a;
      if (!br) {
        const float* w = w0 + c * 9;
        a = b0[c];
        if (e > 0) a += skv[((e - 1) * 8 + stp) * 192 + 96 + c] * w[1];
        a += skv[(e * 8 + stp) * 192 + 96 + c] * w[4];
        if (e < 7) a += skv[((e + 1) * 8 + stp) * 192 + 96 + c] * w[7];
      } else {
        const float* w = w1 + (c - 48) * 9;
        a = b1[c - 48];
        if (e > 0) a += skv[(stp * 8 + e - 1) * 192 + 96 + c] * w[3];
        a += skv[(stp * 8 + e) * 192 + 96 + c] * w[4];
        if (e < 7) a += skv[(stp * 8 + e + 1) * 192 + 96 + c] * w[5];
      }
#pragma unroll
      for (int j = 0; j < 8; ++j) {
        int nj = br ? stp * 8 + j : j * 8 + stp;
        a += P[it][j] * skv[nj * 192 + 96 + c];
      }
      outv[d] = a;
    }
#pragma unroll
    for (int d = 0; d < 16; ++d) skv[ni * 192 + cb + d] = outv[d];
  }
  __syncthreads();

  float* ap = apre + (size_t)win * (64 * 96);
#pragma unroll
  for (int i = 0; i < 24; ++i) {
    int f = i * 256 + t;
    int n = f / 96, o = f % 96;
    ap[f] = skv[n * 192 + (o & 3) * 24 + (o >> 2)];
  }
}

// ---------------------------------------------------------------------------
// Per-batch Gram partials: G[c,d] = sum_n x[n,c] x[n,d].
// ---------------------------------------------------------------------------
__global__ __launch_bounds__(256)
void gramG(const float* __restrict__ X, float* __restrict__ gp) {
  __shared__ float xs[64 * 100];
  const int t = threadIdx.x;
  const int chunk = blockIdx.x, b = blockIdx.y;
  const int c0 = (t >> 4) * 6, d0 = (t & 15) * 6;
  float acc[6][6];
#pragma unroll
  for (int i = 0; i < 6; ++i)
#pragma unroll
    for (int j = 0; j < 6; ++j) acc[i][j] = 0.f;
  const float* base = X + ((size_t)b * LTOK + chunk * 512) * 96;
  for (int tile = 0; tile < 8; ++tile) {
#pragma unroll
    for (int i = 0; i < 6; ++i) {
      int f = t + i * 256;
      int m = f / 24, q = f % 24;
      *(float4*)(&xs[m * 100 + q * 4]) =
          *(const float4*)(base + (size_t)(tile * 64 + m) * 96 + q * 4);
    }
    __syncthreads();
#pragma unroll 4
    for (int nn = 0; nn < 64; ++nn) {
      float a[6], bb[6];
      *(float2*)&a[0] = *(const float2*)&xs[nn * 100 + c0];
      *(float2*)&a[2] = *(const float2*)&xs[nn * 100 + c0 + 2];
      *(float2*)&a[4] = *(const float2*)&xs[nn * 100 + c0 + 4];
      *(float2*)&bb[0] = *(const float2*)&xs[nn * 100 + d0];
      *(float2*)&bb[2] = *(const float2*)&xs[nn * 100 + d0 + 2];
      *(float2*)&bb[4] = *(const float2*)&xs[nn * 100 + d0 + 4];
#pragma unroll
      for (int i = 0; i < 6; ++i)
#pragma unroll
        for (int j = 0; j < 6; ++j) acc[i][j] += a[i] * bb[j];
    }
    __syncthreads();
  }
  float* op = gp + (size_t)(b * 128 + chunk) * 9216;
#pragma unroll
  for (int i = 0; i < 6; ++i)
#pragma unroll
    for (int j = 0; j < 6; ++j) op[(c0 + i) * 96 + d0 + j] = acc[i][j];
}

__global__ __launch_bounds__(256)
void reduceG(const float* __restrict__ gp, float* __restrict__ G) {
  int b = blockIdx.x, part = blockIdx.y;  // (4, 9)
  int e = part * 1024 + threadIdx.x;
  for (int pass = 0; pass < 4; ++pass, e += 256) {
    if (e < 9216) {
      float a = 0.f;
      const float* p = gp + (size_t)b * 128 * 9216 + e;
      for (int ch = 0; ch < 128; ++ch) a += p[(size_t)ch * 9216];
      G[b * 9216 + e] = a;
    }
  }
}

// ---------------------------------------------------------------------------
// RS: per (b,h): S = Wq_h G Wk_h^T; norms from diag; softmax -> A[bh] (16x16)
// ---------------------------------------------------------------------------
__global__ __launch_bounds__(256)
void rs_attn(const float* __restrict__ G, const float* __restrict__ rsqkv,
             const float* __restrict__ rs_scale, float* __restrict__ A) {
  __shared__ float Gs[9216];
  __shared__ float T1[16 * 100];
  __shared__ float T2[16 * 100];
  __shared__ float Wq[16 * 100];
  __shared__ float Wk[16 * 100];
  const int bh = blockIdx.x;
  const int b = bh / 6, h = bh % 6;
  const int t = threadIdx.x;
  for (int e = t; e < 9216; e += 256) Gs[e] = G[b * 9216 + e];
  for (int e = t; e < 1536; e += 256) {
    int r = e / 96, c = e % 96;
    Wq[r * 100 + c] = rsqkv[(size_t)(h * 16 + r) * 96 + c];
    Wk[r * 100 + c] = rsqkv[(size_t)(96 + h * 16 + r) * 96 + c];
  }
  __syncthreads();
  for (int e = t; e < 1536; e += 256) {
    int r = e / 96, c = e % 96;
    float a1 = 0.f, a2 = 0.f;
    for (int k = 0; k < 96; ++k) {
      float g = Gs[k * 96 + c];
      a1 += Wq[r * 100 + k] * g;
      a2 += Wk[r * 100 + k] * g;
    }
    T1[r * 100 + c] = a1;
    T2[r * 100 + c] = a2;
  }
  __syncthreads();
  int c = t >> 4, d = t & 15;
  float s = 0.f, nq = 0.f, nk = 0.f;
  for (int k = 0; k < 96; ++k) {
    float t1 = T1[c * 100 + k];
    s += t1 * Wk[d * 100 + k];
    nq += t1 * Wq[c * 100 + k];
    nk += T2[d * 100 + k] * Wk[d * 100 + k];
  }
  float g = s / (fmaxf(sqrtf(nq), 1e-12f) * fmaxf(sqrtf(nk), 1e-12f)) * rs_scale[h];
  float mx = g;
#pragma unroll
  for (int m = 1; m < 16; m <<= 1) mx = fmaxf(mx, __shfl_xor(mx, m));
  float pb = expf(g - mx);
  float sum = pb;
#pragma unroll
  for (int m = 1; m < 16; m <<= 1) sum += __shfl_xor(sum, m);
  A[bh * 256 + c * 16 + d] = pb / sum;
}

// ---------------------------------------------------------------------------
// W_eff[b] = PW . blockdiag(A_h) . Wv  (96x96 per batch)
// ---------------------------------------------------------------------------
__global__ __launch_bounds__(256)
void rs_weff(const float* __restrict__ A, const float* __restrict__ rsqkv,
             const float* __restrict__ pw, float* __restrict__ weff) {
  __shared__ float Bd[96 * 100];
  __shared__ float As[6 * 256];
  const int b = blockIdx.x;
  const int t = threadIdx.x;
  for (int e = t; e < 1536; e += 256) As[e] = A[b * 1536 + e];
  __syncthreads();
  for (int e = t; e < 9216; e += 256) {
    int c = e / 96, k = e % 96;
    int h = c >> 4, cl = c & 15;
    float a = 0.f;
#pragma unroll
    for (int r = 0; r < 16; ++r)
      a += As[h * 256 + cl * 16 + r] * rsqkv[(size_t)(192 + h * 16 + r) * 96 + k];
    Bd[c * 100 + k] = a;
  }
  __syncthreads();
  const int o0 = (t >> 4) * 6, k0 = (t & 15) * 6;
  float acc[6][6];
#pragma unroll
  for (int i = 0; i < 6; ++i)
#pragma unroll
    for (int j = 0; j < 6; ++j) acc[i][j] = 0.f;
  for (int c = 0; c < 96; ++c) {
    float pv[6], bv[6];
#pragma unroll
    for (int i = 0; i < 6; ++i) pv[i] = pw[(o0 + i) * 96 + c];
#pragma unroll
    for (int j = 0; j < 6; ++j) bv[j] = Bd[c * 100 + k0 + j];
#pragma unroll
    for (int i = 0; i < 6; ++i)
#pragma unroll
      for (int j = 0; j < 6; ++j) acc[i][j] += pv[i] * bv[j];
  }
#pragma unroll
  for (int i = 0; i < 6; ++i)
#pragma unroll
    for (int j = 0; j < 6; ++j)
      weff[b * 9216 + (o0 + i) * 96 + k0 + j] = acc[i][j];
}

// ---------------------------------------------------------------------------
extern "C" void kernel_launch(void* const* d_in, const int* in_sizes, int n_in,
                              void* d_out, int out_size, void* d_ws, size_t ws_size,
                              hipStream_t stream) {
  const float* x = (const float*)d_in[0];
  const float* cvec = (const float*)d_in[1];
  const float* n1w = (const float*)d_in[2];
  const float* n1b = (const float*)d_in[3];
  const float* n2w = (const float*)d_in[4];
  const float* n2b = (const float*)d_in[5];
  const float* ada_w = (const float*)d_in[6];
  const float* ada_b = (const float*)d_in[7];
  const float* qkv_w = (const float*)d_in[8];
  const float* qkv_b = (const float*)d_in[9];
  const float* proj_w = (const float*)d_in[10];
  const float* proj_b = (const float*)d_in[11];
  const float* l0w = (const float*)d_in[12];
  const float* l0b = (const float*)d_in[13];
  const float* l1w = (const float*)d_in[14];
  const float* l1b = (const float*)d_in[15];
  const float* rssc = (const float*)d_in[16];
  const float* rsqkvw = (const float*)d_in[17];
  const float* rsprojw = (const float*)d_in[18];
  const float* fc1w = (const float*)d_in[19];
  const float* fc1b = (const float*)d_in[20];
  const float* fc2w = (const float*)d_in[21];
  const float* fc2b = (const float*)d_in[22];
  float* out = (float*)d_out;

  // ws layout (floats), total 39,405,568 (~150 MiB)
  float* Wf = (float*)d_ws;
  float* MOD = Wf;                       // 4096
  float* WEFF = MOD + 4096;              // 36864
  float* AA = WEFF + 36864;              // 6144
  float* G = AA + 6144;                  // 36864
  float* GRAMP = G + 36864;              // 512*9216 = 4718592
  float* H = GRAMP + 4718592;            // NTOK*96 = 25165824
  float* QKVC = H + (size_t)NTOK * 96;   // 32768*288 = 9437184 (qkv chunks, then u)

  mod_kernel<<<9, 256, 0, stream>>>(cvec, ada_w, ada_b, MOD);
  ln_mod<<<NTOK / 4, 256, 0, stream>>>(x, n1w, n1b, MOD, 0, 96, H, 1);
  for (int ch = 0; ch < NCHUNKQ; ++ch) {
    float* Hc = H + (size_t)ch * RPC * 96;
    gemmB<EPI_PLAIN, 1><<<dim3(RPC / 128, 3), 256, 0, stream>>>(
        Hc, 96, qkv_w, 288, qkv_b, QKVC, nullptr, nullptr, 1, 0);
    win_attn<<<RPC / 64, 256, 0, stream>>>(QKVC, l0w, l0b, l1w, l1b, Hc);
  }
  // proj + window-reverse + residual + gate -> d_out (= x_msa)
  gemmB<EPI_PROJ, 1><<<dim3(NTOK / 128 / 8, 1), 256, 0, stream>>>(
      H, 96, proj_w, 96, proj_b, out, x, MOD, 8, 0);
  // RS channel attention via per-batch Gram
  gramG<<<dim3(128, 4), 256, 0, stream>>>(out, GRAMP);
  reduceG<<<dim3(4, 9), 256, 0, stream>>>(GRAMP, G);
  rs_attn<<<24, 256, 0, stream>>>(G, rsqkvw, rssc, AA);
  rs_weff<<<4, 256, 0, stream>>>(AA, rsqkvw, rsprojw, WEFF);
  // x2 = W_eff . x_msa + x_msa  -> H
  gemmB<EPI_RSOUT, 1><<<dim3(NTOK / 128 / 8, 1), 256, 0, stream>>>(
      out, 96, WEFF, 96, nullptr, H, out, MOD, 8, 0);
  // LN2 + mlp modulation -> d_out (h2), row-major
  ln_mod<<<NTOK / 4, 256, 0, stream>>>(H, n2w, n2b, MOD, 288, 384, out, 0);
  // MLP chunked: fc1+GELU -> u (QKVC), fc2 + gate + residual(x2 in H) -> d_out
  for (int ch = 0; ch < NCHUNKQ; ++ch) {
    const float* h2c = out + (size_t)ch * RPC * 96;
    gemmB<EPI_FC1, 1><<<dim3(RPC / 128, 2), 256, 0, stream>>>(
        h2c, 96, fc1w, 192, fc1b, QKVC, nullptr, nullptr, 1, 0);
    gemmB<EPI_FC2, 2><<<dim3(RPC / 128, 1), 256, 0, stream>>>(
        QKVC, 192, fc2w, 96, fc2b, out, H, MOD, 1, ch * RPC);
  }
}

// Round 6
// 1660.975 us; speedup vs baseline: 7.9554x; 7.9554x over previous
//
#include <hip/hip_runtime.h>
#include <math.h>

// S2TLA block. B=4, L=65536 (256x256), C=96, HEADS=6, WS=8, HID=192.
// GEMM family on MFMA via bf16x3 split (Xh*Wh + Xh*Wl + Xl*Wh), fp32 elsewhere.
// Workspace ~150 MiB; d_out doubles as scratch (x_msa, then h2).

#define LTOK   65536
#define NTOK   (4 * LTOK)        // 262144
#define NCHUNKQ 8
#define RPC (NTOK / NCHUNKQ)     // 32768 rows = 512 windows
#define PADB 104                 // bf16 LDS row pad (208B): uniform bank spread

enum { EPI_PLAIN = 0, EPI_PROJ = 1, EPI_RSOUT = 2, EPI_FC1 = 3, EPI_FC2 = 4 };

typedef __attribute__((ext_vector_type(8))) short short8;
typedef __attribute__((ext_vector_type(4))) float f32x4;

__device__ __forceinline__ unsigned short bf_rne(float f) {
  unsigned u = __float_as_uint(f);
  return (unsigned short)((u + 0x7fffu + ((u >> 16) & 1u)) >> 16);
}
__device__ __forceinline__ void f2bf2(float f, unsigned short& h, unsigned short& l) {
  h = bf_rne(f);
  float fh = __uint_as_float((unsigned)h << 16);
  l = bf_rne(f - fh);
}

// ---------------------------------------------------------------------------
// mod = silu(c) @ ada_w.T + ada_b   -> (4, 576)
// ---------------------------------------------------------------------------
__global__ __launch_bounds__(256)
void mod_kernel(const float* __restrict__ cvec, const float* __restrict__ ada_w,
                const float* __restrict__ ada_b, float* __restrict__ mod) {
  int idx = blockIdx.x * 256 + threadIdx.x;
  if (idx >= 4 * 576) return;
  int b = idx / 576, j = idx % 576;
  const float* cr = cvec + b * 96;
  float acc = ada_b[j];
  for (int c = 0; c < 96; ++c) {
    float cv = cr[c];
    acc += (cv / (1.f + expf(-cv))) * ada_w[j * 96 + c];
  }
  mod[idx] = acc;
}

// ---------------------------------------------------------------------------
// y = LN(x)*(1+sc)+sh per token. window_order=1 writes window-partitioned rows.
// ---------------------------------------------------------------------------
__global__ __launch_bounds__(256)
void ln_mod(const float* __restrict__ X, const float* __restrict__ lnw,
            const float* __restrict__ lnb, const float* __restrict__ mod,
            int sh_off, int sc_off, float* __restrict__ Y, int window_order) {
  int g = blockIdx.x * 4 + (threadIdx.x >> 6);
  int lane = threadIdx.x & 63;
  const float* xr = X + (size_t)g * 96;
  float2 v = make_float2(0.f, 0.f);
  if (lane < 48) v = *(const float2*)(xr + lane * 2);
  float s = v.x + v.y, sq = v.x * v.x + v.y * v.y;
#pragma unroll
  for (int m = 1; m < 64; m <<= 1) {
    s += __shfl_xor(s, m);
    sq += __shfl_xor(sq, m);
  }
  float mu = s * (1.f / 96.f);
  float rs = rsqrtf(sq * (1.f / 96.f) - mu * mu + 1e-5f);
  int b = g >> 16;
  size_t orow;
  if (window_order) {
    int l = g & 65535;
    int y = l >> 8, x = l & 255;
    orow = ((size_t)((b << 10) + ((y >> 3) << 5) + (x >> 3)) << 6) +
           ((y & 7) << 3) + (x & 7);
  } else {
    orow = g;
  }
  if (lane < 48) {
    int c = lane * 2;
    const float* mb = mod + b * 576;
    float2 o;
    o.x = ((v.x - mu) * rs * lnw[c] + lnb[c]) * (1.f + mb[sc_off + c]) + mb[sh_off + c];
    o.y = ((v.y - mu) * rs * lnw[c + 1] + lnb[c + 1]) * (1.f + mb[sc_off + c + 1]) + mb[sh_off + c + 1];
    *(float2*)(Y + orow * 96 + c) = o;
  }
}

// ---------------------------------------------------------------------------
// gemmM: Y[m,n] = sum_k X[m,k]*W[n,k] (+bias), fused epilogues, via MFMA
// bf16x3 split. Block tile 64x96, 4 waves, wave tile 32x48 (2x3 16x16 frags).
// Staging converts fp32 -> (hi,lo) bf16 in LDS. K = 96*kchunks.
// ---------------------------------------------------------------------------
template <int EPI>
__global__ __launch_bounds__(256)
void gemmM(const float* __restrict__ X, int ldx, const float* __restrict__ W,
           int K, const float* __restrict__ bias, float* __restrict__ Y,
           const float* __restrict__ aux, const float* __restrict__ mod,
           int row0) {
  __shared__ __align__(16) unsigned short Xh[64 * PADB];
  __shared__ __align__(16) unsigned short Xl[64 * PADB];
  __shared__ __align__(16) unsigned short Wh[96 * PADB];
  __shared__ __align__(16) unsigned short Wl[96 * PADB];
  const int t = threadIdx.x;
  const int bn = blockIdx.y;
  const int trow = blockIdx.x * 64;
  const int lane = t & 63, wid = t >> 6;
  const int wm = wid >> 1, wn = wid & 1;

  const float* Wb = W;
  if constexpr (EPI == EPI_RSOUT) Wb = W + (size_t)(trow >> 16) * 9216;

  f32x4 acc[2][3];
#pragma unroll
  for (int i = 0; i < 2; ++i)
#pragma unroll
    for (int j = 0; j < 3; ++j) acc[i][j] = (f32x4){0.f, 0.f, 0.f, 0.f};

  const int kchunks = K / 96;
  for (int kc = 0; kc < kchunks; ++kc) {
    // stage X tile (64x96): 6 float4/thread, convert to hi/lo bf16
#pragma unroll
    for (int i = 0; i < 6; ++i) {
      int f = t + i * 256;
      int m = f / 24, q = (f % 24) * 4;
      float4 v = *(const float4*)(X + (size_t)(trow + m) * ldx + kc * 96 + q);
      unsigned short h0, h1, h2, h3, l0, l1, l2, l3;
      f2bf2(v.x, h0, l0); f2bf2(v.y, h1, l1);
      f2bf2(v.z, h2, l2); f2bf2(v.w, h3, l3);
      *(uint2*)(&Xh[m * PADB + q]) =
          make_uint2((unsigned)h0 | ((unsigned)h1 << 16), (unsigned)h2 | ((unsigned)h3 << 16));
      *(uint2*)(&Xl[m * PADB + q]) =
          make_uint2((unsigned)l0 | ((unsigned)l1 << 16), (unsigned)l2 | ((unsigned)l3 << 16));
    }
    // stage W tile (96x96): 9 float4/thread
#pragma unroll
    for (int i = 0; i < 9; ++i) {
      int f = t + i * 256;
      int n = f / 24, q = (f % 24) * 4;
      float4 v = *(const float4*)(Wb + (size_t)(bn * 96 + n) * K + kc * 96 + q);
      unsigned short h0, h1, h2, h3, l0, l1, l2, l3;
      f2bf2(v.x, h0, l0); f2bf2(v.y, h1, l1);
      f2bf2(v.z, h2, l2); f2bf2(v.w, h3, l3);
      *(uint2*)(&Wh[n * PADB + q]) =
          make_uint2((unsigned)h0 | ((unsigned)h1 << 16), (unsigned)h2 | ((unsigned)h3 << 16));
      *(uint2*)(&Wl[n * PADB + q]) =
          make_uint2((unsigned)l0 | ((unsigned)l1 << 16), (unsigned)l2 | ((unsigned)l3 << 16));
    }
    __syncthreads();
#pragma unroll
    for (int kk = 0; kk < 3; ++kk) {
      const int koff = kk * 32 + (lane >> 4) * 8;
      short8 Ah[2], Al[2], Bh[3], Bl[3];
#pragma unroll
      for (int mt = 0; mt < 2; ++mt) {
        int base = (wm * 32 + mt * 16 + (lane & 15)) * PADB + koff;
        Ah[mt] = *(const short8*)(&Xh[base]);
        Al[mt] = *(const short8*)(&Xl[base]);
      }
#pragma unroll
      for (int nt = 0; nt < 3; ++nt) {
        int base = (wn * 48 + nt * 16 + (lane & 15)) * PADB + koff;
        Bh[nt] = *(const short8*)(&Wh[base]);
        Bl[nt] = *(const short8*)(&Wl[base]);
      }
#pragma unroll
      for (int mt = 0; mt < 2; ++mt)
#pragma unroll
        for (int nt = 0; nt < 3; ++nt) {
          acc[mt][nt] = __builtin_amdgcn_mfma_f32_16x16x32_bf16(
              Ah[mt], Bh[nt], acc[mt][nt], 0, 0, 0);
          acc[mt][nt] = __builtin_amdgcn_mfma_f32_16x16x32_bf16(
              Ah[mt], Bl[nt], acc[mt][nt], 0, 0, 0);
          acc[mt][nt] = __builtin_amdgcn_mfma_f32_16x16x32_bf16(
              Al[mt], Bh[nt], acc[mt][nt], 0, 0, 0);
        }
    }
    __syncthreads();
  }

  // epilogue: D elem (mt, nt, r) -> m = wm*32+mt*16+(lane>>4)*4+r, col = lane&15
#pragma unroll
  for (int mt = 0; mt < 2; ++mt)
#pragma unroll
    for (int nt = 0; nt < 3; ++nt)
#pragma unroll
      for (int r = 0; r < 4; ++r) {
        const int row = trow + wm * 32 + mt * 16 + ((lane >> 4) << 2) + r;
        const int col = bn * 96 + wn * 48 + nt * 16 + (lane & 15);
        float v = acc[mt][nt][r];
        if (bias) v += bias[col];
        if constexpr (EPI == EPI_PLAIN) {
          Y[(size_t)row * 288 + col] = v;  // qkv only (N=288)
        } else if constexpr (EPI == EPI_PROJ) {
          int win = row >> 6, n = row & 63;
          int b = win >> 10, wy = (win >> 5) & 31, wx = win & 31;
          int iy = n >> 3, ix = n & 7;
          int l = ((wy << 3) + iy) * 256 + (wx << 3) + ix;
          size_t oi = ((size_t)b * LTOK + l) * 96 + col;
          Y[oi] = aux[oi] + mod[b * 576 + 192 + col] * v;
        } else if constexpr (EPI == EPI_RSOUT) {
          size_t oi = (size_t)row * 96 + col;
          Y[oi] = aux[oi] + v;
        } else if constexpr (EPI == EPI_FC1) {
          Y[(size_t)row * 192 + col] =
              0.5f * v * (1.f + erff(v * 0.70710678118654752440f));
        } else {  // EPI_FC2
          int grow = row0 + row;
          int b = grow >> 16;
          size_t oi = (size_t)grow * 96 + col;
          Y[oi] = aux[oi] + mod[b * 576 + 480 + col] * v;
        }
      }
}

// ---------------------------------------------------------------------------
// Windowed strip attention (both halves) + LePE + channel shuffle.
// One block per 8x8 window; writes apre IN PLACE over its own H rows.
// ---------------------------------------------------------------------------
__global__ __launch_bounds__(256)
void win_attn(const float* __restrict__ qkv, const float* __restrict__ w0,
              const float* __restrict__ b0, const float* __restrict__ w1,
              const float* __restrict__ b1, float* __restrict__ apre) {
  __shared__ float skv[64 * 192];  // [n][0..95]=k, [n][96..191]=v
  const int t = threadIdx.x;
  const int win = blockIdx.x;
  const float* gb = qkv + (size_t)win * (64 * 288);
#pragma unroll
  for (int i = 0; i < 12; ++i) {
    int f = t + i * 256;
    int n = f / 48, q = f % 48;
    *(float4*)(&skv[n * 192 + q * 4]) = *(const float4*)(gb + n * 288 + 96 + q * 4);
  }
  __syncthreads();

  float P[2][8];
  int task[2];
#pragma unroll
  for (int it = 0; it < 2; ++it) {
    int tt = t + it * 256;
    task[it] = (tt < 384) ? tt : -1;
    if (task[it] < 0) continue;
    int br = tt / 192;
    int r = tt % 192;
    int stp = r / 24;
    int h = (r / 8) % 3;
    int e = r % 8;
    int cb = br ? 48 + h * 16 : h * 16;
    int ni = br ? stp * 8 + e : e * 8 + stp;
    float qreg[16];
#pragma unroll
    for (int d = 0; d < 16; ++d) qreg[d] = gb[ni * 288 + cb + d];
    float s[8];
#pragma unroll
    for (int j = 0; j < 8; ++j) {
      int nj = br ? stp * 8 + j : j * 8 + stp;
      float a = 0.f;
#pragma unroll
      for (int d = 0; d < 16; ++d) a += qreg[d] * skv[nj * 192 + cb + d];
      s[j] = a * 0.25f;
    }
    float mx = s[0];
#pragma unroll
    for (int j = 1; j < 8; ++j) mx = fmaxf(mx, s[j]);
    float sum = 0.f;
#pragma unroll
    for (int j = 0; j < 8; ++j) { s[j] = expf(s[j] - mx); sum += s[j]; }
    float inv = 1.f / sum;
#pragma unroll
    for (int j = 0; j < 8; ++j) P[it][j] = s[j] * inv;
  }
  __syncthreads();

#pragma unroll
  for (int it = 0; it < 2; ++it) {
    int tt = task[it];
    if (tt < 0) continue;
    int br = tt / 192;
    int r = tt % 192;
    int stp = r / 24;
    int h = (r / 8) % 3;
    int e = r % 8;
    int cb = br ? 48 + h * 16 : h * 16;
    int ni = br ? stp * 8 + e : e * 8 + stp;
    float outv[16];
#pragma unroll
    for (int d = 0; d < 16; ++d) {
      int c = cb + d;
      float a;
      if (!br) {
        const float* w = w0 + c * 9;
        a = b0[c];
        if (e > 0) a += skv[((e - 1) * 8 + stp) * 192 + 96 + c] * w[1];
        a += skv[(e * 8 + stp) * 192 + 96 + c] * w[4];
        if (e < 7) a += skv[((e + 1) * 8 + stp) * 192 + 96 + c] * w[7];
      } else {
        const float* w = w1 + (c - 48) * 9;
        a = b1[c - 48];
        if (e > 0) a += skv[(stp * 8 + e - 1) * 192 + 96 + c] * w[3];
        a += skv[(stp * 8 + e) * 192 + 96 + c] * w[4];
        if (e < 7) a += skv[(stp * 8 + e + 1) * 192 + 96 + c] * w[5];
      }
#pragma unroll
      for (int j = 0; j < 8; ++j) {
        int nj = br ? stp * 8 + j : j * 8 + stp;
        a += P[it][j] * skv[nj * 192 + 96 + c];
      }
      outv[d] = a;
    }
#pragma unroll
    for (int d = 0; d < 16; ++d) skv[ni * 192 + cb + d] = outv[d];
  }
  __syncthreads();

  float* ap = apre + (size_t)win * (64 * 96);
#pragma unroll
  for (int i = 0; i < 24; ++i) {
    int f = i * 256 + t;
    int n = f / 96, o = f % 96;
    ap[f] = skv[n * 192 + (o & 3) * 24 + (o >> 2)];
  }
}

// ---------------------------------------------------------------------------
// Per-batch Gram partials: G[c,d] = sum_n x[n,c] x[n,d].
// ---------------------------------------------------------------------------
__global__ __launch_bounds__(256)
void gramG(const float* __restrict__ X, float* __restrict__ gp) {
  __shared__ float xs[64 * 100];
  const int t = threadIdx.x;
  const int chunk = blockIdx.x, b = blockIdx.y;
  const int c0 = (t >> 4) * 6, d0 = (t & 15) * 6;
  float acc[6][6];
#pragma unroll
  for (int i = 0; i < 6; ++i)
#pragma unroll
    for (int j = 0; j < 6; ++j) acc[i][j] = 0.f;
  const float* base = X + ((size_t)b * LTOK + chunk * 512) * 96;
  for (int tile = 0; tile < 8; ++tile) {
#pragma unroll
    for (int i = 0; i < 6; ++i) {
      int f = t + i * 256;
      int m = f / 24, q = f % 24;
      *(float4*)(&xs[m * 100 + q * 4]) =
          *(const float4*)(base + (size_t)(tile * 64 + m) * 96 + q * 4);
    }
    __syncthreads();
#pragma unroll 4
    for (int nn = 0; nn < 64; ++nn) {
      float a[6], bb[6];
      *(float2*)&a[0] = *(const float2*)&xs[nn * 100 + c0];
      *(float2*)&a[2] = *(const float2*)&xs[nn * 100 + c0 + 2];
      *(float2*)&a[4] = *(const float2*)&xs[nn * 100 + c0 + 4];
      *(float2*)&bb[0] = *(const float2*)&xs[nn * 100 + d0];
      *(float2*)&bb[2] = *(const float2*)&xs[nn * 100 + d0 + 2];
      *(float2*)&bb[4] = *(const float2*)&xs[nn * 100 + d0 + 4];
#pragma unroll
      for (int i = 0; i < 6; ++i)
#pragma unroll
        for (int j = 0; j < 6; ++j) acc[i][j] += a[i] * bb[j];
    }
    __syncthreads();
  }
  float* op = gp + (size_t)(b * 128 + chunk) * 9216;
#pragma unroll
  for (int i = 0; i < 6; ++i)
#pragma unroll
    for (int j = 0; j < 6; ++j) op[(c0 + i) * 96 + d0 + j] = acc[i][j];
}

__global__ __launch_bounds__(256)
void reduceG(const float* __restrict__ gp, float* __restrict__ G) {
  int b = blockIdx.x, part = blockIdx.y;  // (4, 9)
  int e = part * 1024 + threadIdx.x;
  for (int pass = 0; pass < 4; ++pass, e += 256) {
    if (e < 9216) {
      float a = 0.f;
      const float* p = gp + (size_t)b * 128 * 9216 + e;
      for (int ch = 0; ch < 128; ++ch) a += p[(size_t)ch * 9216];
      G[b * 9216 + e] = a;
    }
  }
}

// ---------------------------------------------------------------------------
// RS: per (b,h): S = Wq_h G Wk_h^T; norms from diag; softmax -> A[bh] (16x16)
// ---------------------------------------------------------------------------
__global__ __launch_bounds__(256)
void rs_attn(const float* __restrict__ G, const float* __restrict__ rsqkv,
             const float* __restrict__ rs_scale, float* __restrict__ A) {
  __shared__ float Gs[9216];
  __shared__ float T1[16 * 100];
  __shared__ float T2[16 * 100];
  __shared__ float Wq[16 * 100];
  __shared__ float Wk[16 * 100];
  const int bh = blockIdx.x;
  const int b = bh / 6, h = bh % 6;
  const int t = threadIdx.x;
  for (int e = t; e < 9216; e += 256) Gs[e] = G[b * 9216 + e];
  for (int e = t; e < 1536; e += 256) {
    int r = e / 96, c = e % 96;
    Wq[r * 100 + c] = rsqkv[(size_t)(h * 16 + r) * 96 + c];
    Wk[r * 100 + c] = rsqkv[(size_t)(96 + h * 16 + r) * 96 + c];
  }
  __syncthreads();
  for (int e = t; e < 1536; e += 256) {
    int r = e / 96, c = e % 96;
    float a1 = 0.f, a2 = 0.f;
    for (int k = 0; k < 96; ++k) {
      float g = Gs[k * 96 + c];
      a1 += Wq[r * 100 + k] * g;
      a2 += Wk[r * 100 + k] * g;
    }
    T1[r * 100 + c] = a1;
    T2[r * 100 + c] = a2;
  }
  __syncthreads();
  int c = t >> 4, d = t & 15;
  float s = 0.f, nq = 0.f, nk = 0.f;
  for (int k = 0; k < 96; ++k) {
    float t1 = T1[c * 100 + k];
    s += t1 * Wk[d * 100 + k];
    nq += t1 * Wq[c * 100 + k];
    nk += T2[d * 100 + k] * Wk[d * 100 + k];
  }
  float g = s / (fmaxf(sqrtf(nq), 1e-12f) * fmaxf(sqrtf(nk), 1e-12f)) * rs_scale[h];
  float mx = g;
#pragma unroll
  for (int m = 1; m < 16; m <<= 1) mx = fmaxf(mx, __shfl_xor(mx, m));
  float pb = expf(g - mx);
  float sum = pb;
#pragma unroll
  for (int m = 1; m < 16; m <<= 1) sum += __shfl_xor(sum, m);
  A[bh * 256 + c * 16 + d] = pb / sum;
}

// ---------------------------------------------------------------------------
// W_eff[b] = PW . blockdiag(A_h) . Wv  (96x96 per batch)
// ---------------------------------------------------------------------------
__global__ __launch_bounds__(256)
void rs_weff(const float* __restrict__ A, const float* __restrict__ rsqkv,
             const float* __restrict__ pw, float* __restrict__ weff) {
  __shared__ float Bd[96 * 100];
  __shared__ float As[6 * 256];
  const int b = blockIdx.x;
  const int t = threadIdx.x;
  for (int e = t; e < 1536; e += 256) As[e] = A[b * 1536 + e];
  __syncthreads();
  for (int e = t; e < 9216; e += 256) {
    int c = e / 96, k = e % 96;
    int h = c >> 4, cl = c & 15;
    float a = 0.f;
#pragma unroll
    for (int r = 0; r < 16; ++r)
      a += As[h * 256 + cl * 16 + r] * rsqkv[(size_t)(192 + h * 16 + r) * 96 + k];
    Bd[c * 100 + k] = a;
  }
  __syncthreads();
  const int o0 = (t >> 4) * 6, k0 = (t & 15) * 6;
  float acc[6][6];
#pragma unroll
  for (int i = 0; i < 6; ++i)
#pragma unroll
    for (int j = 0; j < 6; ++j) acc[i][j] = 0.f;
  for (int c = 0; c < 96; ++c) {
    float pv[6], bv[6];
#pragma unroll
    for (int i = 0; i < 6; ++i) pv[i] = pw[(o0 + i) * 96 + c];
#pragma unroll
    for (int j = 0; j < 6; ++j) bv[j] = Bd[c * 100 + k0 + j];
#pragma unroll
    for (int i = 0; i < 6; ++i)
#pragma unroll
      for (int j = 0; j < 6; ++j) acc[i][j] += pv[i] * bv[j];
  }
#pragma unroll
  for (int i = 0; i < 6; ++i)
#pragma unroll
    for (int j = 0; j < 6; ++j)
      weff[b * 9216 + (o0 + i) * 96 + k0 + j] = acc[i][j];
}

// ---------------------------------------------------------------------------
extern "C" void kernel_launch(void* const* d_in, const int* in_sizes, int n_in,
                              void* d_out, int out_size, void* d_ws, size_t ws_size,
                              hipStream_t stream) {
  const float* x = (const float*)d_in[0];
  const float* cvec = (const float*)d_in[1];
  const float* n1w = (const float*)d_in[2];
  const float* n1b = (const float*)d_in[3];
  const float* n2w = (const float*)d_in[4];
  const float* n2b = (const float*)d_in[5];
  const float* ada_w = (const float*)d_in[6];
  const float* ada_b = (const float*)d_in[7];
  const float* qkv_w = (const float*)d_in[8];
  const float* qkv_b = (const float*)d_in[9];
  const float* proj_w = (const float*)d_in[10];
  const float* proj_b = (const float*)d_in[11];
  const float* l0w = (const float*)d_in[12];
  const float* l0b = (const float*)d_in[13];
  const float* l1w = (const float*)d_in[14];
  const float* l1b = (const float*)d_in[15];
  const float* rssc = (const float*)d_in[16];
  const float* rsqkvw = (const float*)d_in[17];
  const float* rsprojw = (const float*)d_in[18];
  const float* fc1w = (const float*)d_in[19];
  const float* fc1b = (const float*)d_in[20];
  const float* fc2w = (const float*)d_in[21];
  const float* fc2b = (const float*)d_in[22];
  float* out = (float*)d_out;

  // ws layout (floats), total 39,405,568 (~150 MiB)
  float* Wf = (float*)d_ws;
  float* MOD = Wf;                       // 4096
  float* WEFF = MOD + 4096;              // 36864
  float* AA = WEFF + 36864;              // 6144
  float* G = AA + 6144;                  // 36864
  float* GRAMP = G + 36864;              // 512*9216 = 4718592
  float* H = GRAMP + 4718592;            // NTOK*96 = 25165824
  float* QKVC = H + (size_t)NTOK * 96;   // 32768*288 = 9437184 (qkv chunks, then u)

  mod_kernel<<<9, 256, 0, stream>>>(cvec, ada_w, ada_b, MOD);
  ln_mod<<<NTOK / 4, 256, 0, stream>>>(x, n1w, n1b, MOD, 0, 96, H, 1);
  for (int ch = 0; ch < NCHUNKQ; ++ch) {
    float* Hc = H + (size_t)ch * RPC * 96;
    gemmM<EPI_PLAIN><<<dim3(RPC / 64, 3), 256, 0, stream>>>(
        Hc, 96, qkv_w, 96, qkv_b, QKVC, nullptr, nullptr, 0);
    win_attn<<<RPC / 64, 256, 0, stream>>>(QKVC, l0w, l0b, l1w, l1b, Hc);
  }
  // proj + window-reverse + residual + gate -> d_out (= x_msa)
  gemmM<EPI_PROJ><<<dim3(NTOK / 64, 1), 256, 0, stream>>>(
      H, 96, proj_w, 96, proj_b, out, x, MOD, 0);
  // RS channel attention via per-batch Gram
  gramG<<<dim3(128, 4), 256, 0, stream>>>(out, GRAMP);
  reduceG<<<dim3(4, 9), 256, 0, stream>>>(GRAMP, G);
  rs_attn<<<24, 256, 0, stream>>>(G, rsqkvw, rssc, AA);
  rs_weff<<<4, 256, 0, stream>>>(AA, rsqkvw, rsprojw, WEFF);
  // x2 = W_eff . x_msa + x_msa  -> H
  gemmM<EPI_RSOUT><<<dim3(NTOK / 64, 1), 256, 0, stream>>>(
      out, 96, WEFF, 96, nullptr, H, out, MOD, 0);
  // LN2 + mlp modulation -> d_out (h2), row-major
  ln_mod<<<NTOK / 4, 256, 0, stream>>>(H, n2w, n2b, MOD, 288, 384, out, 0);
  // MLP chunked: fc1+GELU -> u (QKVC), fc2 + gate + residual(x2 in H) -> d_out
  for (int ch = 0; ch < NCHUNKQ; ++ch) {
    const float* h2c = out + (size_t)ch * RPC * 96;
    gemmM<EPI_FC1><<<dim3(RPC / 64, 2), 256, 0, stream>>>(
        h2c, 96, fc1w, 96, fc1b, QKVC, nullptr, nullptr, 0);
    gemmM<EPI_FC2><<<dim3(RPC / 64, 1), 256, 0, stream>>>(
        QKVC, 192, fc2w, 192, fc2b, out, H, MOD, ch * RPC);
  }
}